// Round 6
// baseline (446.540 us; speedup 1.0000x reference)
//
#include <hip/hip_runtime.h>

#define N_NODES 50000
#define N_EDGES 600000
#define F 128

// ---------- ws layout (16-aligned) ----------
#define WT_OFF   0                 // 294,912 B   bf16 W [r][o][i], r=8 is loop_weight
#define H2_OFF   294912            // 12,800,000  bf16 h
#define GATE_OFF 13094912          // 1,600,000   sigmoid gates [r][n]
#define CNT_OFF  14694912          // 200,064     dst histogram
#define BASE_OFF 14894976          // 200,064     exclusive scan (+sentinel at [N_NODES])
#define CUR_OFF  15095040          // 200,064     scatter cursor
#define REC_OFF  15295104          // 4,800,000   {src|rel<<16, scale} per edge, dst-sorted
#define WS_NEED  ((size_t)20095104)

#define LDA 136   // padded short stride: 272B rows, 16B-aligned

typedef __attribute__((ext_vector_type(8))) short short8;
typedef __attribute__((ext_vector_type(4))) float floatx4;

__device__ inline unsigned short f32_to_bf16(float f) {
    unsigned u = __float_as_uint(f);
    unsigned r = u + 0x7fff + ((u >> 16) & 1);
    return (unsigned short)(r >> 16);
}
__device__ inline float bf16lo(unsigned m) { return __uint_as_float(m << 16); }
__device__ inline float bf16hi(unsigned m) { return __uint_as_float(m & 0xffff0000u); }
__device__ inline float sigmoidf(float x) { return 1.f / (1.f + __expf(-x)); }

// ---------- k_prep: W->bf16 prep, h->bf16, gates, dst histogram — one dispatch ----------
__global__ void k_prep(const float* __restrict__ h, const float* __restrict__ gw,
                       const float* __restrict__ W, const float* __restrict__ LW,
                       const int* __restrict__ dst,
                       unsigned short* __restrict__ h2, float* __restrict__ gate,
                       unsigned short* __restrict__ Wt, int* __restrict__ cnt) {
    int gid = blockIdx.x * 256 + threadIdx.x;
    if (gid < N_EDGES) atomicAdd(&cnt[dst[gid]], 1);
    if (gid < 9 * 128 * 128) {
        int r = gid >> 14, rem = gid & 16383, i = rem >> 7, o = rem & 127;
        float v = (r < 8) ? W[(r << 14) + (i << 7) + o] : LW[(i << 7) + o];
        Wt[(r << 14) + (o << 7) + i] = f32_to_bf16(v);
    }
    int wave = threadIdx.x >> 6, lane = threadIdx.x & 63;
    int n = blockIdx.x * 4 + wave;            // grid 12500 -> exactly 50000
    float2 hv = *(const float2*)(h + (size_t)n * F + lane * 2);
    unsigned val = (unsigned)f32_to_bf16(hv.x) | ((unsigned)f32_to_bf16(hv.y) << 16);
    *(unsigned*)(h2 + (size_t)n * F + lane * 2) = val;
    #pragma unroll
    for (int r = 0; r < 8; ++r) {
        float2 wv = *(const float2*)(gw + r * F + lane * 2);
        float p = hv.x * wv.x + hv.y * wv.y;
        #pragma unroll
        for (int off = 32; off; off >>= 1) p += __shfl_xor(p, off);
        if (lane == 0) gate[r * N_NODES + n] = sigmoidf(p);
    }
}

// ---------- k_scan: single-block exclusive scan of 50000 bins ----------
__global__ __launch_bounds__(1024) void k_scan(const int* __restrict__ cnt,
                                               int* __restrict__ base,
                                               int* __restrict__ cursor) {
    __shared__ int wpart[16];
    const int CH = 49;                        // 1024*49 = 50176 >= 50000
    int t = threadIdx.x, lane = t & 63, w = t >> 6;
    int st = t * CH;
    int s = 0;
    for (int i = 0; i < CH; ++i) {
        int idx = st + i;
        if (idx < N_NODES) s += cnt[idx];
    }
    int x = s;
    #pragma unroll
    for (int off = 1; off < 64; off <<= 1) {
        int tt = __shfl_up(x, off);
        if (lane >= off) x += tt;
    }
    if (lane == 63) wpart[w] = x;
    __syncthreads();
    if (t < 16) {
        int y = wpart[t];
        #pragma unroll
        for (int off = 1; off < 16; off <<= 1) {
            int tt = __shfl_up(y, off);
            if (t >= off) y += tt;
        }
        wpart[t] = y;
    }
    __syncthreads();
    int pre = (w > 0) ? wpart[w - 1] : 0;
    int run = pre + x - s;                    // exclusive prefix at chunk start
    for (int i = 0; i < CH; ++i) {
        int idx = st + i;
        if (idx < N_NODES) {
            int v = cnt[idx];
            base[idx] = run;
            cursor[idx] = run;
            run += v;
        }
    }
    if (t == 0) base[N_NODES] = N_EDGES;
}

// ---------- k_scatter: dst-sorted 8B records {src | rel<<16, scale} ----------
__global__ void k_scatter(const int* __restrict__ src, const int* __restrict__ dst,
                          const int* __restrict__ rel, const float* __restrict__ norm,
                          const float* __restrict__ gate,
                          int* __restrict__ cursor, int2* __restrict__ rec) {
    int e = blockIdx.x * 256 + threadIdx.x;
    if (e >= N_EDGES) return;
    int d = dst[e], r = rel[e], s = src[e];
    int pos = atomicAdd(&cursor[d], 1);
    float sc = norm[e] * gate[r * N_NODES + s];
    rec[pos] = make_int2(s | (r << 16), __float_as_int(sc));
}

// ---------- k_fused: 64-node tile, 16 waves; records loaded once, ballot-filtered per kb ----------
__global__ __launch_bounds__(1024, 2) void k_fused(const unsigned short* __restrict__ h2,
                                                   const unsigned short* __restrict__ Wt,
                                                   const int2* __restrict__ rec,
                                                   const int* __restrict__ base,
                                                   const float* __restrict__ bias,
                                                   float* __restrict__ out) {
    __shared__ unsigned short sA[64 * LDA];    // 17 KB
    __shared__ unsigned short sB[128 * LDA];   // 34 KB
    int tid = threadIdx.x;
    int w = tid >> 6, lane = tid & 63;
    int lrow = lane & 15, quad = lane >> 4;
    int nb = blockIdx.x * 64;                  // grid 782 covers 50048 rows
    int mblk = w >> 2, nblk = w & 3;
    int n0 = nb + w * 4;

    // load this wave's 4-row segment bounds and (up to 64) records ONCE
    int b = N_EDGES;
    if (lane < 5) {
        int idx = n0 + lane;
        if (idx > N_NODES) idx = N_NODES;
        b = base[idx];
    }
    int b0 = __shfl(b, 0), b1 = __shfl(b, 1), b2 = __shfl(b, 2);
    int b3 = __shfl(b, 3), b4 = __shfl(b, 4);
    int degT = b4 - b0;
    int nreg = degT < 64 ? degT : 64;
    int srcrel = 0, scl = 0;
    if (lane < nreg) {
        int2 rc = rec[b0 + lane];
        srcrel = rc.x; scl = rc.y;
    }
    int idxa = b0 + lane;
    int rowid = (idxa >= b1) + (idxa >= b2) + (idxa >= b3);
    int myrel = (srcrel >> 16) & 7;
    bool valid = lane < nreg;

    floatx4 acc[2];
    acc[0] = (floatx4){0.f, 0.f, 0.f, 0.f};
    acc[1] = (floatx4){0.f, 0.f, 0.f, 0.f};

    for (int kb = 0; kb < 9; ++kb) {
        __syncthreads();   // previous MFMA reads of sA/sB complete
        // stage W_kb
        #pragma unroll
        for (int it = 0; it < 2; ++it) {
            int G = it * 1024 + tid;
            int row = G >> 4, gr = G & 15;
            *(uint4*)(&sB[row * LDA + gr * 8]) = *(const uint4*)(Wt + (kb << 14) + G * 8);
        }
        if (kb < 8) {
            #pragma unroll
            for (int rr = 0; rr < 4; ++rr) {
                unsigned long long m = __ballot(valid && rowid == rr && myrel == kb);
                float a0 = 0.f, a1 = 0.f;
                if (m) {                        // 2-deep pipelined gather over set bits
                    int j = __ffsll(m) - 1; m &= m - 1;
                    float sc = __int_as_float(__shfl(scl, j));
                    int sj = __shfl(srcrel, j) & 0xffff;
                    unsigned mv = *(const unsigned*)(h2 + (size_t)sj * F + lane * 2);
                    while (m) {
                        int j2 = __ffsll(m) - 1; m &= m - 1;
                        float sc2 = __int_as_float(__shfl(scl, j2));
                        int sj2 = __shfl(srcrel, j2) & 0xffff;
                        unsigned mv2 = *(const unsigned*)(h2 + (size_t)sj2 * F + lane * 2);
                        a0 += sc * bf16lo(mv);
                        a1 += sc * bf16hi(mv);
                        sc = sc2; mv = mv2;
                    }
                    a0 += sc * bf16lo(mv);
                    a1 += sc * bf16hi(mv);
                }
                if (degT > 64) {                // rare overflow: uniform direct walk
                    int brr  = (rr == 0) ? b0 : ((rr == 1) ? b1 : ((rr == 2) ? b2 : b3));
                    int brr1 = (rr == 0) ? b1 : ((rr == 1) ? b2 : ((rr == 2) ? b3 : b4));
                    int jlo = b0 + 64 > brr ? b0 + 64 : brr;
                    for (int j = jlo; j < brr1; ++j) {
                        int2 rc = rec[j];
                        if (((rc.x >> 16) & 7) == kb) {
                            float sc = __int_as_float(rc.y);
                            int sj = rc.x & 0xffff;
                            unsigned mv = *(const unsigned*)(h2 + (size_t)sj * F + lane * 2);
                            a0 += sc * bf16lo(mv);
                            a1 += sc * bf16hi(mv);
                        }
                    }
                }
                int row = w * 4 + rr;
                unsigned val = (unsigned)f32_to_bf16(a0) | ((unsigned)f32_to_bf16(a1) << 16);
                ((unsigned*)sA)[row * (LDA / 2) + lane] = val;
            }
        } else {
            // kb=8 self-loop: stage h2 rows directly (1024 granules)
            int row = tid >> 4, gr = tid & 15;
            int node = nb + row;
            uint4 v;
            if (node < N_NODES) v = *(const uint4*)(h2 + (size_t)node * F + gr * 8);
            else { v.x = 0; v.y = 0; v.z = 0; v.w = 0; }
            *(uint4*)(&sA[row * LDA + gr * 8]) = v;
        }
        __syncthreads();
        #pragma unroll
        for (int kt = 0; kt < 4; ++kt) {
            short8 a = *(const short8*)(&sA[(mblk * 16 + lrow) * LDA + kt * 32 + quad * 8]);
            #pragma unroll
            for (int nt = 0; nt < 2; ++nt) {
                short8 bb = *(const short8*)(&sB[(nblk * 32 + nt * 16 + lrow) * LDA + kt * 32 + quad * 8]);
                acc[nt] = __builtin_amdgcn_mfma_f32_16x16x32_bf16(a, bb, acc[nt], 0, 0, 0);
            }
        }
    }
    // epilogue: bias + relu
    #pragma unroll
    for (int nt = 0; nt < 2; ++nt) {
        int col = nblk * 32 + nt * 16 + lrow;
        float bv = bias[col];
        #pragma unroll
        for (int g = 0; g < 4; ++g) {
            int row = nb + mblk * 16 + quad * 4 + g;
            if (row < N_NODES)
                out[(size_t)row * F + col] = fmaxf(acc[nt][g] + bv, 0.f);
        }
    }
}

// ---------- ws-free safety fallback ----------
__global__ void k_edges_fb(const float* __restrict__ h, const float* __restrict__ W,
                           const float* __restrict__ gw, const float* __restrict__ norm,
                           const int* __restrict__ src, const int* __restrict__ dst,
                           const int* __restrict__ rel, float* __restrict__ out) {
    int wave = threadIdx.x >> 6, lane = threadIdx.x & 63;
    int e = blockIdx.x * 4 + wave;
    if (e >= N_EDGES) return;
    int s = src[e], d = dst[e], r = rel[e];
    float2 hv = *(const float2*)(h + (size_t)s * F + lane * 2);
    float2 gv = *(const float2*)(gw + r * F + lane * 2);
    float p = hv.x * gv.x + hv.y * gv.y;
    #pragma unroll
    for (int off = 32; off; off >>= 1) p += __shfl_xor(p, off);
    float scale = norm[e] * sigmoidf(p);
    const float* wr = W + ((size_t)r << 14);
    float a0 = 0.f, a1 = 0.f;
    for (int i2 = 0; i2 < 64; ++i2) {
        float x0 = __shfl(hv.x, i2), x1 = __shfl(hv.y, i2);
        a0 += x0 * wr[(2 * i2) * F + lane]      + x1 * wr[(2 * i2 + 1) * F + lane];
        a1 += x0 * wr[(2 * i2) * F + 64 + lane] + x1 * wr[(2 * i2 + 1) * F + 64 + lane];
    }
    unsafeAtomicAdd(out + (size_t)d * F + lane,      a0 * scale);
    unsafeAtomicAdd(out + (size_t)d * F + 64 + lane, a1 * scale);
}

__global__ void k_final_fb(const float* __restrict__ h, const float* __restrict__ LW,
                           const float* __restrict__ bias, float* __restrict__ out) {
    int wave = threadIdx.x >> 6, lane = threadIdx.x & 63;
    int n = blockIdx.x * 4 + wave;
    if (n >= N_NODES) return;
    float2 hv = *(const float2*)(h + (size_t)n * F + lane * 2);
    float a0 = 0.f, a1 = 0.f;
    for (int i2 = 0; i2 < 64; ++i2) {
        float x0 = __shfl(hv.x, i2), x1 = __shfl(hv.y, i2);
        a0 += x0 * LW[(2 * i2) * F + lane]      + x1 * LW[(2 * i2 + 1) * F + lane];
        a1 += x0 * LW[(2 * i2) * F + 64 + lane] + x1 * LW[(2 * i2 + 1) * F + 64 + lane];
    }
    float* op = out + (size_t)n * F;
    op[lane]      = fmaxf(op[lane]      + bias[lane]      + a0, 0.f);
    op[64 + lane] = fmaxf(op[64 + lane] + bias[64 + lane] + a1, 0.f);
}

extern "C" void kernel_launch(void* const* d_in, const int* in_sizes, int n_in,
                              void* d_out, int out_size, void* d_ws, size_t ws_size,
                              hipStream_t stream) {
    const float* h    = (const float*)d_in[0];
    const float* W    = (const float*)d_in[1];
    const float* gw   = (const float*)d_in[2];
    const float* bias = (const float*)d_in[3];
    const float* lw   = (const float*)d_in[4];
    const float* norm = (const float*)d_in[5];
    const int* src    = (const int*)d_in[6];
    const int* dst    = (const int*)d_in[7];
    const int* rel    = (const int*)d_in[8];
    float* out = (float*)d_out;

    if (ws_size >= WS_NEED) {
        unsigned short* Wt   = (unsigned short*)((char*)d_ws + WT_OFF);
        unsigned short* h2   = (unsigned short*)((char*)d_ws + H2_OFF);
        float*          gate = (float*)((char*)d_ws + GATE_OFF);
        int*            cnt  = (int*)((char*)d_ws + CNT_OFF);
        int*            base = (int*)((char*)d_ws + BASE_OFF);
        int*            cur  = (int*)((char*)d_ws + CUR_OFF);
        int2*           rec  = (int2*)((char*)d_ws + REC_OFF);

        hipMemsetAsync(cnt, 0, N_NODES * sizeof(int), stream);
        k_prep<<<12500, 256, 0, stream>>>(h, gw, W, lw, dst, h2, gate, Wt, cnt);
        k_scan<<<1, 1024, 0, stream>>>(cnt, base, cur);
        k_scatter<<<2344, 256, 0, stream>>>(src, dst, rel, norm, gate, cur, rec);
        k_fused<<<782, 1024, 0, stream>>>(h2, Wt, rec, base, bias, out);
    } else {
        hipMemsetAsync(d_out, 0, (size_t)out_size * sizeof(float), stream);
        k_edges_fb<<<150000, 256, 0, stream>>>(h, W, gw, norm, src, dst, rel, out);
        k_final_fb<<<12500, 256, 0, stream>>>(h, lw, bias, out);
    }
}